// Round 7
// baseline (1279.721 us; speedup 1.0000x reference)
//
#include <hip/hip_runtime.h>
#include <cstdint>

#define HH 72
#define NR 4
#define NTH 256
#define NBLK 512
#define TT 512

typedef __attribute__((ext_vector_type(8))) short short8;
typedef __attribute__((ext_vector_type(4))) float f32x4;

#if __has_builtin(__builtin_amdgcn_exp2f)
#define EXP2(x) __builtin_amdgcn_exp2f(x)
#else
#define EXP2(x) exp2f(x)
#endif
#if __has_builtin(__builtin_amdgcn_rcpf)
#define RCP(x) __builtin_amdgcn_rcpf(x)
#else
#define RCP(x) (1.0f/(x))
#endif

__device__ __forceinline__ float fsig(float x) {
  float e = EXP2(x * -1.442695040888963f);
  return RCP(1.0f + e);
}
__device__ __forceinline__ float ftanh(float x) {
  float e = EXP2(x * -2.885390081777927f);
  return fmaf(2.0f, RCP(1.0f + e), -1.0f);
}

__device__ __forceinline__ unsigned bf16rne(float v) {
  unsigned b = __float_as_uint(v);
  return (b + 0x7FFFu + ((b >> 16) & 1u)) >> 16;
}
__device__ __forceinline__ unsigned packHiLo(float v) {
  unsigned hi = bf16rne(v);
  float hf = __uint_as_float(hi << 16);
  unsigned lo = bf16rne(v - hf);
  return hi | (lo << 16);
}

// B-fragment ushort index for contraction-dim k, batch col m (0..15, real 0..3).
__device__ __forceinline__ int bidx(int k, int m) {
  return ((k >> 5)*4 + ((k >> 3) & 3))*128 + m*8 + (k & 7);
}

// lane-xor swizzles (BitMode: offset = xor<<10 | 0x1F)
__device__ __forceinline__ float swz4 (float v) { return __int_as_float(__builtin_amdgcn_ds_swizzle(__float_as_int(v), 0x101F)); }
__device__ __forceinline__ float swz8 (float v) { return __int_as_float(__builtin_amdgcn_ds_swizzle(__float_as_int(v), 0x201F)); }
__device__ __forceinline__ float swz12(float v) { return __int_as_float(__builtin_amdgcn_ds_swizzle(__float_as_int(v), 0x301F)); }

__device__ __forceinline__ float cellUpd(float ig, float fg, float gg, float og, float& c) {
  c = fmaf(fsig(fg), c, fsig(ig)*ftanh(gg));
  return fsig(og)*ftanh(c);
}

// accumulate 4 rows: A[r] += W_ * P_[r]
#define FMA4(A, W_, P_) { \
  const float4 _fa = *(const float4*)(P_); \
  A[0] = fmaf((W_), _fa.x, A[0]); A[1] = fmaf((W_), _fa.y, A[1]); \
  A[2] = fmaf((W_), _fa.z, A[2]); A[3] = fmaf((W_), _fa.w, A[3]); }

// counting sort of rows by h_lens (ascending)
__global__ void cfm_sort(const int* __restrict__ h_lens, int* __restrict__ perm) {
  __shared__ int hist[257];
  __shared__ int offs[257];
  const int t = threadIdx.x; // 256
  for (int i = t; i < 257; i += 256) hist[i] = 0;
  __syncthreads();
  for (int i = t; i < 2048; i += 256) {
    int bkt = min(max(h_lens[i] - 256, 0), 256);
    atomicAdd(&hist[bkt], 1);
  }
  __syncthreads();
  if (t == 0) { int s = 0; for (int i = 0; i < 257; ++i) { offs[i] = s; s += hist[i]; } }
  __syncthreads();
  for (int i = t; i < 2048; i += 256) {
    int bkt = min(max(h_lens[i] - 256, 0), 256);
    int pos = atomicAdd(&offs[bkt], 1);
    perm[pos] = i;
  }
}

__global__ __launch_bounds__(NTH, 3)
void cfm_main(const float* __restrict__ x, const float* __restrict__ rnn,
              const float* __restrict__ deltas, const int* __restrict__ h_lens,
              const float* __restrict__ W_ih, const float* __restrict__ W_hh,
              const float* __restrict__ b_ih, const float* __restrict__ b_hh,
              const float* __restrict__ eW1, const float* __restrict__ eb1,
              const float* __restrict__ eW2, const float* __restrict__ eb2,
              const float* __restrict__ eW3, const float* __restrict__ eb3,
              const float* __restrict__ dW1, const float* __restrict__ db1,
              const float* __restrict__ dW2, const float* __restrict__ db2,
              const float* __restrict__ dW3, const float* __restrict__ db3,
              const int* __restrict__ perm, float* __restrict__ out)
{
  __shared__ __align__(16) unsigned short bHiS[2][1536];
  __shared__ __align__(16) unsigned short bLoS[2][1536];
  __shared__ __align__(16) float gS[1152];         // enc z1S / dec d2S  [n][4]
  __shared__ __align__(16) float rnnS[1152];       // rnn chunk; enc z2S / dec d1S
  __shared__ __align__(16) float snapP[NR][HH];
  __shared__ __align__(16) float snapC[NR][HH];
  __shared__ __align__(16) float hS[HH][NR];       // decoder dec_in
  __shared__ __align__(16) float xS[8][NR];
  __shared__ int brS[NR];
  __shared__ int idxS[NR];
  __shared__ float dS[NR];

  const int t  = threadIdx.x;
  const int bb = blockIdx.x;
  // folded mapping: pair longest with shortest for adjacent block IDs
  const int pgrp = (bb & 1) ? (NBLK - 1 - (bb >> 1)) : (bb >> 1);

  for (int i = t; i < 1536; i += NTH) { ((unsigned*)bHiS)[i] = 0; ((unsigned*)bLoS)[i] = 0; }

  if (t < NR) {
    int row = perm ? perm[pgrp*NR + t] : (pgrp*NR + t);
    brS[t]  = row;
    idxS[t] = h_lens[row] - 1;   // in [255, 511]
  }
  __syncthreads();

  int maxIdx = idxS[0];
  #pragma unroll
  for (int r = 1; r < NR; ++r) maxIdx = max(maxIdx, idxS[r]);

  const int lane = t & 63;
  const int wv   = t >> 6;                          // 4 waves
  const int col  = lane & 15;
  const int q_a  = lane >> 4;
  const int base = (wv < 2) ? wv*5 : 10 + (wv - 2)*4;   // tiles: w0:0-4 w1:5-9 w2:10-13 w3:14-17
  const int nt   = (wv < 2) ? 5 : 4;
  const int g    = col >> 2;                        // col group -> tile base+g
  const int c    = col & 3;                         // batch col (real)
  const int cidxE = idxS[c];
  const int uA = 4*(base + g) + q_a;                // primary unit
  const int uB = 4*(base + 4) + q_a;                // secondary (nt==5, g==0)
  float cstA = 0.f, cstB = 0.f;

  // ---------------- encoder: 8 -> 256 -> 256 -> 64 ----------------
  if (t < 32) { int r = t >> 3, k = t & 7; xS[k][r] = x[brS[r]*8 + k]; }
  __syncthreads();

  float* z1S = gS;   // [k][4]
  {
    float acc[NR];
    float b = eb1[t];
    #pragma unroll
    for (int r = 0; r < NR; ++r) acc[r] = b;
    #pragma unroll
    for (int k = 0; k < 8; ++k) { float w = eW1[t*8 + k]; FMA4(acc, w, &xS[k][0]); }
    #pragma unroll
    for (int r = 0; r < NR; ++r) z1S[t*4 + r] = ftanh(acc[r]);
  }
  __syncthreads();
  float* z2S = rnnS; // [k][4]
  {
    float acc[NR];
    float b = eb2[t];
    #pragma unroll
    for (int r = 0; r < NR; ++r) acc[r] = b;
    const float4* w4 = (const float4*)(eW2 + t*256);
    #pragma unroll 4
    for (int k4 = 0; k4 < 64; ++k4) {
      float4 w = w4[k4];
      FMA4(acc, w.x, z1S + (4*k4+0)*4);
      FMA4(acc, w.y, z1S + (4*k4+1)*4);
      FMA4(acc, w.z, z1S + (4*k4+2)*4);
      FMA4(acc, w.w, z1S + (4*k4+3)*4);
    }
    #pragma unroll
    for (int r = 0; r < NR; ++r) z2S[t*4 + r] = ftanh(acc[r]);
  }
  __syncthreads();
  if (t < 64) {                       // h0 (linear) -> B-frag k = 8+t, buffer 0
    float acc[NR];
    float b = eb3[t];
    #pragma unroll
    for (int r = 0; r < NR; ++r) acc[r] = b;
    const float4* w4 = (const float4*)(eW3 + t*256);
    #pragma unroll 4
    for (int k4 = 0; k4 < 64; ++k4) {
      float4 w = w4[k4];
      FMA4(acc, w.x, z2S + (4*k4+0)*4);
      FMA4(acc, w.y, z2S + (4*k4+1)*4);
      FMA4(acc, w.z, z2S + (4*k4+2)*4);
      FMA4(acc, w.w, z2S + (4*k4+3)*4);
    }
    int u = 8 + t;
    #pragma unroll
    for (int r = 0; r < NR; ++r) {
      unsigned p = packHiLo(acc[r]);
      int id = bidx(u, r);
      bHiS[0][id] = (unsigned short)p;
      bLoS[0][id] = (unsigned short)(p >> 16);
    }
  } else if (t < 96) {                // x part -> k = 0..7, buffer 0
    int tt2 = t - 64; int r = tt2 >> 3, k = tt2 & 7;
    unsigned p = packHiLo(xS[k][r]);
    int id = bidx(k, r);
    bHiS[0][id] = (unsigned short)p;
    bLoS[0][id] = (unsigned short)(p >> 16);
  }

  // ---------------- weights as A-fragments (gate-permuted rows) ----------------
  // n' = 4*unit + gate ; src row = gate*72 + unit. A[m=n'][k], k = kt*32+q_a*8+j.
  short8 Ahi[5][3], Alo[5][3];
  f32x4 biasq[5];
  #pragma unroll
  for (int i = 0; i < 5; ++i) {
    int ii = (i < nt) ? i : 0;
    int u = 4*(base + ii) + q_a;
    biasq[i].x = b_ih[u]       + b_hh[u];
    biasq[i].y = b_ih[72 + u]  + b_hh[72 + u];
    biasq[i].z = b_ih[144 + u] + b_hh[144 + u];
    biasq[i].w = b_ih[216 + u] + b_hh[216 + u];
    int nprime = (base + ii)*16 + col;
    int srcrow = (nprime & 3)*72 + (nprime >> 2);
    #pragma unroll
    for (int kt = 0; kt < 3; ++kt) {
      unsigned h16[8], l16[8];
      #pragma unroll
      for (int j = 0; j < 8; ++j) {
        int k = kt*32 + q_a*8 + j;
        float v = 0.f;
        if (k < 72)      v = W_hh[srcrow*HH + k];
        else if (k < 81) v = W_ih[srcrow*9 + (k - 72)];
        unsigned hi = bf16rne(v);
        h16[j] = hi;
        l16[j] = bf16rne(v - __uint_as_float(hi << 16));
      }
      union { unsigned u4[4]; short8 s; } ch, cl;
      #pragma unroll
      for (int d = 0; d < 4; ++d) {
        ch.u4[d] = h16[2*d] | (h16[2*d+1] << 16);
        cl.u4[d] = l16[2*d] | (l16[2*d+1] << 16);
      }
      Ahi[i][kt] = ch.s;
      Alo[i][kt] = cl.s;
    }
  }

  // ---------------- LSTM over time: one barrier per step ----------------
  int step = 0;
  int par = 0;
  __syncthreads();
  for (int chunk = 0; chunk*32 <= maxIdx; ++chunk) {
    // stage 32 steps of rnn_input -> rnnS[tc][r][k]
    for (int e = t; e < 1152; e += NTH) {
      int r = e / 288, pos = e % 288;
      int tc = pos / 9, kk = pos - tc*9;
      rnnS[tc*36 + r*9 + kk] = rnn[brS[r]*4608 + chunk*288 + pos];
    }
    __syncthreads();
    if (t < 36) {                   // xt for first step of chunk -> buffer par
      int r = t / 9, kk = t - r*9;
      unsigned p = packHiLo(rnnS[t]);
      int id = bidx(72 + kk, r);
      bHiS[par][id] = (unsigned short)p;
      bLoS[par][id] = (unsigned short)(p >> 16);
    }
    __syncthreads();
    int lim = min(31, maxIdx - chunk*32);
    for (int tc = 0; tc <= lim; ++tc, ++step) {
      const int np = par ^ 1;
      short8 bh[3], bl[3];
      #pragma unroll
      for (int kt = 0; kt < 3; ++kt) {
        int rb = (kt*4 + q_a)*128 + col*8;
        bh[kt] = *(const short8*)&bHiS[par][rb];
        bl[kt] = *(const short8*)&bLoS[par][rb];
      }
      f32x4 acc[5];
      #pragma unroll
      for (int i = 0; i < 5; ++i) acc[i] = biasq[i];
      #pragma unroll
      for (int kt = 0; kt < 3; ++kt) {
        #pragma unroll
        for (int i = 0; i < 5; ++i) {
          if (i < nt) {
            acc[i] = __builtin_amdgcn_mfma_f32_16x16x32_bf16(Ahi[i][kt], bh[kt], acc[i], 0, 0, 0);
            acc[i] = __builtin_amdgcn_mfma_f32_16x16x32_bf16(Alo[i][kt], bh[kt], acc[i], 0, 0, 0);
            acc[i] = __builtin_amdgcn_mfma_f32_16x16x32_bf16(Ahi[i][kt], bl[kt], acc[i], 0, 0, 0);
          }
        }
      }
      // fan tiles 1..3 out to col groups 1..3 via lane-xor swizzles
      float s1x = swz4 (acc[1].x), s1y = swz4 (acc[1].y), s1z = swz4 (acc[1].z), s1w = swz4 (acc[1].w);
      float s2x = swz8 (acc[2].x), s2y = swz8 (acc[2].y), s2z = swz8 (acc[2].z), s2w = swz8 (acc[2].w);
      float s3x = swz12(acc[3].x), s3y = swz12(acc[3].y), s3z = swz12(acc[3].z), s3w = swz12(acc[3].w);
      {
        float ig = (g == 0) ? acc[0].x : (g == 1) ? s1x : (g == 2) ? s2x : s3x;
        float fg = (g == 0) ? acc[0].y : (g == 1) ? s1y : (g == 2) ? s2y : s3y;
        float gg = (g == 0) ? acc[0].z : (g == 1) ? s1z : (g == 2) ? s2z : s3z;
        float og = (g == 0) ? acc[0].w : (g == 1) ? s1w : (g == 2) ? s2w : s3w;
        float hv = cellUpd(ig, fg, gg, og, cstA);
        unsigned p = packHiLo(hv);
        int id = bidx(uA, c);
        bHiS[np][id] = (unsigned short)p;
        bLoS[np][id] = (unsigned short)(p >> 16);
        if (step == cidxE - 1) snapP[c][uA] = hv;
        if (step == cidxE)     snapC[c][uA] = hv;
      }
      if (nt == 5 && g == 0) {       // secondary unit: tile base+4
        float hv = cellUpd(acc[4].x, acc[4].y, acc[4].z, acc[4].w, cstB);
        unsigned p = packHiLo(hv);
        int id = bidx(uB, c);
        bHiS[np][id] = (unsigned short)p;
        bLoS[np][id] = (unsigned short)(p >> 16);
        if (step == cidxE - 1) snapP[c][uB] = hv;
        if (step == cidxE)     snapC[c][uB] = hv;
      }
      if (tc < 31 && t < 36) {      // xt for next step -> buffer np
        int r = t / 9, kk = t - r*9;
        unsigned p = packHiLo(rnnS[(tc+1)*36 + t]);
        int id = bidx(72 + kk, r);
        bHiS[np][id] = (unsigned short)p;
        bLoS[np][id] = (unsigned short)(p >> 16);
      }
      __syncthreads();
      par = np;
    }
  }

  // ---------------- decoder: 72 -> 288 -> 288 -> 8 ----------------
  if (t < NR) dS[t] = deltas[brS[t]*TT + idxS[t]];
  __syncthreads();

  // build dec_in into hS[u][r]  (288 = 72*4 elements)
  for (int p = t; p < 288; p += NTH) {
    int u = p % 72, r = p / 72;
    float d = dS[r];
    float sp = snapP[r][u], sc = snapC[r][u];
    hS[u][r] = fmaf(d, sc - sp, sp);
  }
  __syncthreads();

  // layer1: 288 x 72
  float* d1S = rnnS; // [n][4]
  for (int n = t; n < 288; n += NTH) {
    float acc[NR];
    float b = db1[n];
    #pragma unroll
    for (int r = 0; r < NR; ++r) acc[r] = b;
    const float4* w4 = (const float4*)(dW1 + n*HH);
    #pragma unroll 2
    for (int k4 = 0; k4 < 18; ++k4) {
      float4 w = w4[k4];
      FMA4(acc, w.x, &hS[4*k4+0][0]);
      FMA4(acc, w.y, &hS[4*k4+1][0]);
      FMA4(acc, w.z, &hS[4*k4+2][0]);
      FMA4(acc, w.w, &hS[4*k4+3][0]);
    }
    #pragma unroll
    for (int r = 0; r < NR; ++r) d1S[n*4 + r] = ftanh(acc[r]);
  }
  __syncthreads();

  // layer2: 288 x 288
  float* d2S = gS;   // [n][4]
  for (int n = t; n < 288; n += NTH) {
    float acc[NR];
    float b = db2[n];
    #pragma unroll
    for (int r = 0; r < NR; ++r) acc[r] = b;
    const float4* w4 = (const float4*)(dW2 + n*288);
    #pragma unroll 4
    for (int k4 = 0; k4 < 72; ++k4) {
      float4 w = w4[k4];
      FMA4(acc, w.x, d1S + (4*k4+0)*4);
      FMA4(acc, w.y, d1S + (4*k4+1)*4);
      FMA4(acc, w.z, d1S + (4*k4+2)*4);
      FMA4(acc, w.w, d1S + (4*k4+3)*4);
    }
    #pragma unroll
    for (int r = 0; r < NR; ++r) d2S[n*4 + r] = ftanh(acc[r]);
  }
  __syncthreads();

  // layer3: 8 x 288 (linear) + scatter store
  if (t < 32) {
    int o = t & 7, r = t >> 3;
    float acc3 = db3[o];
    const float* wr = dW3 + o*288;
    #pragma unroll 4
    for (int k = 0; k < 288; ++k) acc3 = fmaf(wr[k], d2S[k*4 + r], acc3);
    out[brS[r]*8 + o] = acc3;
  }
}

extern "C" void kernel_launch(void* const* d_in, const int* in_sizes, int n_in,
                              void* d_out, int out_size, void* d_ws, size_t ws_size,
                              hipStream_t stream) {
  const float* x      = (const float*)d_in[0];
  const float* rnn    = (const float*)d_in[1];
  const float* deltas = (const float*)d_in[2];
  const int*   h_lens = (const int*)  d_in[3];
  const float* W_ih   = (const float*)d_in[4];
  const float* W_hh   = (const float*)d_in[5];
  const float* b_ih   = (const float*)d_in[6];
  const float* b_hh   = (const float*)d_in[7];
  const float* eW1    = (const float*)d_in[8];
  const float* eb1    = (const float*)d_in[9];
  const float* eW2    = (const float*)d_in[10];
  const float* eb2    = (const float*)d_in[11];
  const float* eW3    = (const float*)d_in[12];
  const float* eb3    = (const float*)d_in[13];
  const float* dW1    = (const float*)d_in[14];
  const float* db1    = (const float*)d_in[15];
  const float* dW2    = (const float*)d_in[16];
  const float* db2    = (const float*)d_in[17];
  const float* dW3    = (const float*)d_in[18];
  const float* db3    = (const float*)d_in[19];
  float* out = (float*)d_out;

  int* perm = nullptr;
  if (ws_size >= 2048 * sizeof(int)) {
    perm = (int*)d_ws;
    cfm_sort<<<1, 256, 0, stream>>>(h_lens, perm);
  }
  cfm_main<<<NBLK, NTH, 0, stream>>>(x, rnn, deltas, h_lens, W_ih, W_hh, b_ih, b_hh,
                                     eW1, eb1, eW2, eb2, eW3, eb3,
                                     dW1, db1, dW2, db2, dW3, db3,
                                     perm, out);
}

// Round 8
// 678.402 us; speedup vs baseline: 1.8864x; 1.8864x over previous
//
#include <hip/hip_runtime.h>
#include <cstdint>

#define HH 72
#define NR 4
#define NTH 512
#define NBLK 512
#define TT 512

typedef __attribute__((ext_vector_type(8))) short short8;
typedef __attribute__((ext_vector_type(4))) float f32x4;

#if __has_builtin(__builtin_amdgcn_exp2f)
#define EXP2(x) __builtin_amdgcn_exp2f(x)
#else
#define EXP2(x) exp2f(x)
#endif
#if __has_builtin(__builtin_amdgcn_rcpf)
#define RCP(x) __builtin_amdgcn_rcpf(x)
#else
#define RCP(x) (1.0f/(x))
#endif

__device__ __forceinline__ float fsig(float x) {
  float e = EXP2(x * -1.442695040888963f);
  return RCP(1.0f + e);
}
__device__ __forceinline__ float ftanh(float x) {
  float e = EXP2(x * -2.885390081777927f);
  return fmaf(2.0f, RCP(1.0f + e), -1.0f);
}

__device__ __forceinline__ unsigned bf16rne(float v) {
  unsigned b = __float_as_uint(v);
  return (b + 0x7FFFu + ((b >> 16) & 1u)) >> 16;
}
__device__ __forceinline__ unsigned packHiLo(float v) {
  unsigned hi = bf16rne(v);
  float hf = __uint_as_float(hi << 16);
  unsigned lo = bf16rne(v - hf);
  return hi | (lo << 16);
}

// B-fragment ushort index for contraction-dim k, batch col m (real m: 0..3).
__device__ __forceinline__ int bidx(int k, int m) {
  return ((k >> 5)*4 + ((k >> 3) & 3))*128 + m*8 + (k & 7);
}

// lane-xor swizzles (BitMode: offset = xor<<10 | 0x1F)
__device__ __forceinline__ float swz4(float v) { return __int_as_float(__builtin_amdgcn_ds_swizzle(__float_as_int(v), 0x101F)); }
__device__ __forceinline__ float swz8(float v) { return __int_as_float(__builtin_amdgcn_ds_swizzle(__float_as_int(v), 0x201F)); }

__device__ __forceinline__ float cellUpd(float ig, float fg, float gg, float og, float& c) {
  c = fmaf(fsig(fg), c, fsig(ig)*ftanh(gg));
  return fsig(og)*ftanh(c);
}

// accumulate 4 rows: A[r] += W_ * P_[r]
#define FMA4(A, W_, P_) { \
  const float4 _fa = *(const float4*)(P_); \
  A[0] = fmaf((W_), _fa.x, A[0]); A[1] = fmaf((W_), _fa.y, A[1]); \
  A[2] = fmaf((W_), _fa.z, A[2]); A[3] = fmaf((W_), _fa.w, A[3]); }

// counting sort of rows by h_lens (ascending)
__global__ void cfm_sort(const int* __restrict__ h_lens, int* __restrict__ perm) {
  __shared__ int hist[257];
  __shared__ int offs[257];
  const int t = threadIdx.x; // 256
  for (int i = t; i < 257; i += 256) hist[i] = 0;
  __syncthreads();
  for (int i = t; i < 2048; i += 256) {
    int bkt = min(max(h_lens[i] - 256, 0), 256);
    atomicAdd(&hist[bkt], 1);
  }
  __syncthreads();
  if (t == 0) { int s = 0; for (int i = 0; i < 257; ++i) { offs[i] = s; s += hist[i]; } }
  __syncthreads();
  for (int i = t; i < 2048; i += 256) {
    int bkt = min(max(h_lens[i] - 256, 0), 256);
    int pos = atomicAdd(&offs[bkt], 1);
    perm[pos] = i;
  }
}

__global__ __launch_bounds__(NTH, 4)   // 4 waves/EU -> 2 blocks/CU, VGPR cap 128
void cfm_main(const float* __restrict__ x, const float* __restrict__ rnn,
              const float* __restrict__ deltas, const int* __restrict__ h_lens,
              const float* __restrict__ W_ih, const float* __restrict__ W_hh,
              const float* __restrict__ b_ih, const float* __restrict__ b_hh,
              const float* __restrict__ eW1, const float* __restrict__ eb1,
              const float* __restrict__ eW2, const float* __restrict__ eb2,
              const float* __restrict__ eW3, const float* __restrict__ eb3,
              const float* __restrict__ dW1, const float* __restrict__ db1,
              const float* __restrict__ dW2, const float* __restrict__ db2,
              const float* __restrict__ dW3, const float* __restrict__ db3,
              const int* __restrict__ perm, float* __restrict__ out)
{
  __shared__ __align__(16) unsigned short bHiS[2][1536];
  __shared__ __align__(16) unsigned short bLoS[2][1536];
  __shared__ __align__(16) float gS[1152];         // enc z1S / dec d2S  [n][4]
  __shared__ __align__(16) float rnnS[1152];       // rnn chunk; enc z2S / dec d1S
  __shared__ __align__(16) float snapP[NR][HH];
  __shared__ __align__(16) float snapC[NR][HH];
  __shared__ __align__(16) float hS[HH][NR];       // decoder dec_in
  __shared__ __align__(16) float xS[8][NR];
  __shared__ int brS[NR];
  __shared__ int idxS[NR];
  __shared__ float dS[NR];

  const int t  = threadIdx.x;
  const int bb = blockIdx.x;
  // pairing for round-robin dispatch: blocks c and c+256 land on the same CU;
  // give them the c-th shortest and c-th longest row groups.
  const int pgrp = (bb < 256) ? bb : (767 - bb);

  for (int i = t; i < 1536; i += NTH) { ((unsigned*)bHiS)[i] = 0; ((unsigned*)bLoS)[i] = 0; }

  if (t < NR) {
    int row = perm ? perm[pgrp*NR + t] : (pgrp*NR + t);
    brS[t]  = row;
    idxS[t] = h_lens[row] - 1;   // in [255, 511]
  }
  __syncthreads();

  int maxIdx = idxS[0];
  #pragma unroll
  for (int r = 1; r < NR; ++r) maxIdx = max(maxIdx, idxS[r]);

  const int lane = t & 63;
  const int wv   = t >> 6;                          // 8 waves
  const int col  = lane & 15;
  const int q_a  = lane >> 4;
  const int base = (wv < 2) ? wv*3 : 6 + (wv - 2)*2;  // tiles: w0:0-2 w1:3-5 w2..7: 2 each
  const int nt   = (wv < 2) ? 3 : 2;
  const int g    = col >> 2;                        // col group -> tile base+g
  const int c    = col & 3;                         // batch col (real)
  const bool act = (g < nt);
  const int cidxE = idxS[c];
  const int uA = 4*(base + (act ? g : 0)) + q_a;    // unit owned (if act)
  float cstA = 0.f;

  // ---------------- encoder: 8 -> 256 -> 256 -> 64 ----------------
  if (t < 32) { int r = t >> 3, k = t & 7; xS[k][r] = x[brS[r]*8 + k]; }
  __syncthreads();

  float* z1S = gS;   // [k][4]
  if (t < 256) {
    float acc[NR];
    float b = eb1[t];
    #pragma unroll
    for (int r = 0; r < NR; ++r) acc[r] = b;
    #pragma unroll
    for (int k = 0; k < 8; ++k) { float w = eW1[t*8 + k]; FMA4(acc, w, &xS[k][0]); }
    #pragma unroll
    for (int r = 0; r < NR; ++r) z1S[t*4 + r] = ftanh(acc[r]);
  }
  __syncthreads();
  float* z2S = rnnS; // [k][4]
  if (t < 256) {
    float acc[NR];
    float b = eb2[t];
    #pragma unroll
    for (int r = 0; r < NR; ++r) acc[r] = b;
    const float4* w4 = (const float4*)(eW2 + t*256);
    #pragma unroll 4
    for (int k4 = 0; k4 < 64; ++k4) {
      float4 w = w4[k4];
      FMA4(acc, w.x, z1S + (4*k4+0)*4);
      FMA4(acc, w.y, z1S + (4*k4+1)*4);
      FMA4(acc, w.z, z1S + (4*k4+2)*4);
      FMA4(acc, w.w, z1S + (4*k4+3)*4);
    }
    #pragma unroll
    for (int r = 0; r < NR; ++r) z2S[t*4 + r] = ftanh(acc[r]);
  }
  __syncthreads();
  if (t < 64) {                       // h0 (linear) -> B-frag k = 8+t, buffer 0
    float acc[NR];
    float b = eb3[t];
    #pragma unroll
    for (int r = 0; r < NR; ++r) acc[r] = b;
    const float4* w4 = (const float4*)(eW3 + t*256);
    #pragma unroll 4
    for (int k4 = 0; k4 < 64; ++k4) {
      float4 w = w4[k4];
      FMA4(acc, w.x, z2S + (4*k4+0)*4);
      FMA4(acc, w.y, z2S + (4*k4+1)*4);
      FMA4(acc, w.z, z2S + (4*k4+2)*4);
      FMA4(acc, w.w, z2S + (4*k4+3)*4);
    }
    int u = 8 + t;
    #pragma unroll
    for (int r = 0; r < NR; ++r) {
      unsigned p = packHiLo(acc[r]);
      int id = bidx(u, r);
      bHiS[0][id] = (unsigned short)p;
      bLoS[0][id] = (unsigned short)(p >> 16);
    }
  } else if (t < 96) {                // x part -> k = 0..7, buffer 0
    int tt2 = t - 64; int r = tt2 >> 3, k = tt2 & 7;
    unsigned p = packHiLo(xS[k][r]);
    int id = bidx(k, r);
    bHiS[0][id] = (unsigned short)p;
    bLoS[0][id] = (unsigned short)(p >> 16);
  }

  // ---------------- weights as A-fragments (gate-permuted rows) ----------------
  // n' = 4*unit + gate ; src row = gate*72 + unit. A[m=n'][k], k = kt*32+q_a*8+j.
  short8 Ahi[3][3], Alo[3][3];
  f32x4 biasq[3];
  #pragma unroll
  for (int i = 0; i < 3; ++i) {
    int ii = (i < nt) ? i : 0;
    int u = 4*(base + ii) + q_a;
    biasq[i].x = b_ih[u]       + b_hh[u];
    biasq[i].y = b_ih[72 + u]  + b_hh[72 + u];
    biasq[i].z = b_ih[144 + u] + b_hh[144 + u];
    biasq[i].w = b_ih[216 + u] + b_hh[216 + u];
    int nprime = (base + ii)*16 + col;
    int srcrow = (nprime & 3)*72 + (nprime >> 2);
    #pragma unroll
    for (int kt = 0; kt < 3; ++kt) {
      unsigned h16[8], l16[8];
      #pragma unroll
      for (int j = 0; j < 8; ++j) {
        int k = kt*32 + q_a*8 + j;
        float v = 0.f;
        if (k < 72)      v = W_hh[srcrow*HH + k];
        else if (k < 81) v = W_ih[srcrow*9 + (k - 72)];
        unsigned hi = bf16rne(v);
        h16[j] = hi;
        l16[j] = bf16rne(v - __uint_as_float(hi << 16));
      }
      union { unsigned u4[4]; short8 s; } ch, cl;
      #pragma unroll
      for (int d = 0; d < 4; ++d) {
        ch.u4[d] = h16[2*d] | (h16[2*d+1] << 16);
        cl.u4[d] = l16[2*d] | (l16[2*d+1] << 16);
      }
      Ahi[i][kt] = ch.s;
      Alo[i][kt] = cl.s;
    }
  }

  // ---------------- LSTM over time: one barrier per step ----------------
  int step = 0;
  int par = 0;
  __syncthreads();
  for (int chunk = 0; chunk*32 <= maxIdx; ++chunk) {
    // stage 32 steps of rnn_input -> rnnS[tc][r][k]
    for (int e = t; e < 1152; e += NTH) {
      int r = e / 288, pos = e % 288;
      int tc = pos / 9, kk = pos - tc*9;
      rnnS[tc*36 + r*9 + kk] = rnn[brS[r]*4608 + chunk*288 + pos];
    }
    __syncthreads();
    if (t < 36) {                   // xt for first step of chunk -> buffer par
      int r = t / 9, kk = t - r*9;
      unsigned p = packHiLo(rnnS[t]);
      int id = bidx(72 + kk, r);
      bHiS[par][id] = (unsigned short)p;
      bLoS[par][id] = (unsigned short)(p >> 16);
    }
    __syncthreads();
    int lim = min(31, maxIdx - chunk*32);
    for (int tc = 0; tc <= lim; ++tc, ++step) {
      const int np = par ^ 1;
      short8 bh[3], bl[3];
      #pragma unroll
      for (int kt = 0; kt < 3; ++kt) {
        int rb = (kt*4 + q_a)*128 + col*8;
        bh[kt] = *(const short8*)&bHiS[par][rb];
        bl[kt] = *(const short8*)&bLoS[par][rb];
      }
      f32x4 acc[3];
      #pragma unroll
      for (int i = 0; i < 3; ++i) acc[i] = biasq[i];
      #pragma unroll
      for (int kt = 0; kt < 3; ++kt) {
        #pragma unroll
        for (int i = 0; i < 3; ++i) {
          if (i < nt) {
            acc[i] = __builtin_amdgcn_mfma_f32_16x16x32_bf16(Ahi[i][kt], bh[kt], acc[i], 0, 0, 0);
            acc[i] = __builtin_amdgcn_mfma_f32_16x16x32_bf16(Alo[i][kt], bh[kt], acc[i], 0, 0, 0);
            acc[i] = __builtin_amdgcn_mfma_f32_16x16x32_bf16(Ahi[i][kt], bl[kt], acc[i], 0, 0, 0);
          }
        }
      }
      // fan tile base+1 -> col group 1 (swz4), tile base+2 -> group 2 (swz8)
      float s1x = swz4(acc[1].x), s1y = swz4(acc[1].y), s1z = swz4(acc[1].z), s1w = swz4(acc[1].w);
      float s2x = swz8(acc[2].x), s2y = swz8(acc[2].y), s2z = swz8(acc[2].z), s2w = swz8(acc[2].w);
      if (act) {
        float ig = (g == 0) ? acc[0].x : (g == 1) ? s1x : s2x;
        float fg = (g == 0) ? acc[0].y : (g == 1) ? s1y : s2y;
        float gg = (g == 0) ? acc[0].z : (g == 1) ? s1z : s2z;
        float og = (g == 0) ? acc[0].w : (g == 1) ? s1w : s2w;
        float hv = cellUpd(ig, fg, gg, og, cstA);
        unsigned p = packHiLo(hv);
        int id = bidx(uA, c);
        bHiS[np][id] = (unsigned short)p;
        bLoS[np][id] = (unsigned short)(p >> 16);
        if (step == cidxE - 1) snapP[c][uA] = hv;
        if (step == cidxE)     snapC[c][uA] = hv;
      }
      if (tc < 31 && t < 36) {      // xt for next step -> buffer np
        int r = t / 9, kk = t - r*9;
        unsigned p = packHiLo(rnnS[(tc+1)*36 + t]);
        int id = bidx(72 + kk, r);
        bHiS[np][id] = (unsigned short)p;
        bLoS[np][id] = (unsigned short)(p >> 16);
      }
      __syncthreads();
      par = np;
    }
  }

  // ---------------- decoder: 72 -> 288 -> 288 -> 8 ----------------
  if (t < NR) dS[t] = deltas[brS[t]*TT + idxS[t]];
  __syncthreads();

  // build dec_in into hS[u][r]  (288 = 72*4 elements)
  for (int p = t; p < 288; p += NTH) {
    int u = p % 72, r = p / 72;
    float d = dS[r];
    float sp = snapP[r][u], sc = snapC[r][u];
    hS[u][r] = fmaf(d, sc - sp, sp);
  }
  __syncthreads();

  // layer1: 288 x 72
  float* d1S = rnnS; // [n][4]
  for (int n = t; n < 288; n += NTH) {
    float acc[NR];
    float b = db1[n];
    #pragma unroll
    for (int r = 0; r < NR; ++r) acc[r] = b;
    const float4* w4 = (const float4*)(dW1 + n*HH);
    #pragma unroll 2
    for (int k4 = 0; k4 < 18; ++k4) {
      float4 w = w4[k4];
      FMA4(acc, w.x, &hS[4*k4+0][0]);
      FMA4(acc, w.y, &hS[4*k4+1][0]);
      FMA4(acc, w.z, &hS[4*k4+2][0]);
      FMA4(acc, w.w, &hS[4*k4+3][0]);
    }
    #pragma unroll
    for (int r = 0; r < NR; ++r) d1S[n*4 + r] = ftanh(acc[r]);
  }
  __syncthreads();

  // layer2: 288 x 288
  float* d2S = gS;   // [n][4]
  for (int n = t; n < 288; n += NTH) {
    float acc[NR];
    float b = db2[n];
    #pragma unroll
    for (int r = 0; r < NR; ++r) acc[r] = b;
    const float4* w4 = (const float4*)(dW2 + n*288);
    #pragma unroll 4
    for (int k4 = 0; k4 < 72; ++k4) {
      float4 w = w4[k4];
      FMA4(acc, w.x, d1S + (4*k4+0)*4);
      FMA4(acc, w.y, d1S + (4*k4+1)*4);
      FMA4(acc, w.z, d1S + (4*k4+2)*4);
      FMA4(acc, w.w, d1S + (4*k4+3)*4);
    }
    #pragma unroll
    for (int r = 0; r < NR; ++r) d2S[n*4 + r] = ftanh(acc[r]);
  }
  __syncthreads();

  // layer3: 8 x 288 (linear) + scatter store
  if (t < 32) {
    int o = t & 7, r = t >> 3;
    float acc3 = db3[o];
    const float* wr = dW3 + o*288;
    #pragma unroll 4
    for (int k = 0; k < 288; ++k) acc3 = fmaf(wr[k], d2S[k*4 + r], acc3);
    out[brS[r]*8 + o] = acc3;
  }
}

extern "C" void kernel_launch(void* const* d_in, const int* in_sizes, int n_in,
                              void* d_out, int out_size, void* d_ws, size_t ws_size,
                              hipStream_t stream) {
  const float* x      = (const float*)d_in[0];
  const float* rnn    = (const float*)d_in[1];
  const float* deltas = (const float*)d_in[2];
  const int*   h_lens = (const int*)  d_in[3];
  const float* W_ih   = (const float*)d_in[4];
  const float* W_hh   = (const float*)d_in[5];
  const float* b_ih   = (const float*)d_in[6];
  const float* b_hh   = (const float*)d_in[7];
  const float* eW1    = (const float*)d_in[8];
  const float* eb1    = (const float*)d_in[9];
  const float* eW2    = (const float*)d_in[10];
  const float* eb2    = (const float*)d_in[11];
  const float* eW3    = (const float*)d_in[12];
  const float* eb3    = (const float*)d_in[13];
  const float* dW1    = (const float*)d_in[14];
  const float* db1    = (const float*)d_in[15];
  const float* dW2    = (const float*)d_in[16];
  const float* db2    = (const float*)d_in[17];
  const float* dW3    = (const float*)d_in[18];
  const float* db3    = (const float*)d_in[19];
  float* out = (float*)d_out;

  int* perm = nullptr;
  if (ws_size >= 2048 * sizeof(int)) {
    perm = (int*)d_ws;
    cfm_sort<<<1, 256, 0, stream>>>(h_lens, perm);
  }
  cfm_main<<<NBLK, NTH, 0, stream>>>(x, rnn, deltas, h_lens, W_ih, W_hh, b_ih, b_hh,
                                     eW1, eb1, eW2, eb2, eW3, eb3,
                                     dW1, db1, dW2, db2, dW3, db3,
                                     perm, out);
}

// Round 9
// 437.669 us; speedup vs baseline: 2.9239x; 1.5500x over previous
//
#include <hip/hip_runtime.h>
#include <cstdint>

#define HH 72
#define NR 4
#define NTH 512
#define NBLK 512
#define TT 512

typedef __attribute__((ext_vector_type(8))) _Float16 half8;
typedef __attribute__((ext_vector_type(4))) float f32x4;

#if __has_builtin(__builtin_amdgcn_exp2f)
#define EXP2(x) __builtin_amdgcn_exp2f(x)
#else
#define EXP2(x) exp2f(x)
#endif
#if __has_builtin(__builtin_amdgcn_rcpf)
#define RCP(x) __builtin_amdgcn_rcpf(x)
#else
#define RCP(x) (1.0f/(x))
#endif

__device__ __forceinline__ float fsig(float x) {
  float e = EXP2(x * -1.442695040888963f);
  return RCP(1.0f + e);
}
__device__ __forceinline__ float ftanh(float x) {
  float e = EXP2(x * -2.885390081777927f);
  return fmaf(2.0f, RCP(1.0f + e), -1.0f);
}

// fp32 -> fp16 bits (RNE via v_cvt_f16_f32)
__device__ __forceinline__ unsigned short f2h(float v) {
  union { _Float16 h; unsigned short u; } cv;
  cv.h = (_Float16)v;
  return cv.u;
}

// fragment ushort index for contraction-dim k, batch col m (real m: 0..3).
// Layout [kt*4+q][m][8]: 8 contiguous fp16 -> one ds_read_b128 per (group,m).
__device__ __forceinline__ int bidx(int k, int m) {
  return ((k >> 5)*4 + ((k >> 3) & 3))*128 + m*8 + (k & 7);
}

// lane-xor swizzles (BitMode: offset = xor<<10 | 0x1F)
__device__ __forceinline__ float swz4(float v) { return __int_as_float(__builtin_amdgcn_ds_swizzle(__float_as_int(v), 0x101F)); }
__device__ __forceinline__ float swz8(float v) { return __int_as_float(__builtin_amdgcn_ds_swizzle(__float_as_int(v), 0x201F)); }

__device__ __forceinline__ float cellUpd(float ig, float fg, float gg, float og, float& c) {
  c = fmaf(fsig(fg), c, fsig(ig)*ftanh(gg));
  return fsig(og)*ftanh(c);
}

// accumulate 4 rows: A[r] += W_ * P_[r]
#define FMA4(A, W_, P_) { \
  const float4 _fa = *(const float4*)(P_); \
  A[0] = fmaf((W_), _fa.x, A[0]); A[1] = fmaf((W_), _fa.y, A[1]); \
  A[2] = fmaf((W_), _fa.z, A[2]); A[3] = fmaf((W_), _fa.w, A[3]); }

// counting sort of rows by h_lens (ascending)
__global__ void cfm_sort(const int* __restrict__ h_lens, int* __restrict__ perm) {
  __shared__ int hist[257];
  __shared__ int offs[257];
  const int t = threadIdx.x; // 256
  for (int i = t; i < 257; i += 256) hist[i] = 0;
  __syncthreads();
  for (int i = t; i < 2048; i += 256) {
    int bkt = min(max(h_lens[i] - 256, 0), 256);
    atomicAdd(&hist[bkt], 1);
  }
  __syncthreads();
  if (t == 0) { int s = 0; for (int i = 0; i < 257; ++i) { offs[i] = s; s += hist[i]; } }
  __syncthreads();
  for (int i = t; i < 2048; i += 256) {
    int bkt = min(max(h_lens[i] - 256, 0), 256);
    int pos = atomicAdd(&offs[bkt], 1);
    perm[pos] = i;
  }
}

__global__ __launch_bounds__(NTH, 4)   // 4 waves/EU -> 2 blocks/CU; reg demand ~100 fits 128
void cfm_main(const float* __restrict__ x, const float* __restrict__ rnn,
              const float* __restrict__ deltas, const int* __restrict__ h_lens,
              const float* __restrict__ W_ih, const float* __restrict__ W_hh,
              const float* __restrict__ b_ih, const float* __restrict__ b_hh,
              const float* __restrict__ eW1, const float* __restrict__ eb1,
              const float* __restrict__ eW2, const float* __restrict__ eb2,
              const float* __restrict__ eW3, const float* __restrict__ eb3,
              const float* __restrict__ dW1, const float* __restrict__ db1,
              const float* __restrict__ dW2, const float* __restrict__ db2,
              const float* __restrict__ dW3, const float* __restrict__ db3,
              const int* __restrict__ perm, float* __restrict__ out)
{
  __shared__ __align__(16) unsigned short hF[2][1536];   // fp16 [h|xt|pad] B-fragments, dbuf
  __shared__ __align__(16) float gS[1152];               // enc z1S / dec d2S  [n][4]
  __shared__ __align__(16) float rnnS[1152];             // rnn chunk; enc z2S / dec d1S
  __shared__ __align__(16) float snapP[NR][HH];
  __shared__ __align__(16) float snapC[NR][HH];
  __shared__ __align__(16) float hS[HH][NR];             // decoder dec_in
  __shared__ __align__(16) float xS[8][NR];
  __shared__ int brS[NR];
  __shared__ int idxS[NR];
  __shared__ float dS[NR];

  const int t  = threadIdx.x;
  const int bb = blockIdx.x;
  // round-robin dispatch pairing: blocks c and c+256 share a CU -> give them
  // the c-th shortest and c-th longest row groups.
  const int pgrp = (bb < 256) ? bb : (767 - bb);

  for (int i = t; i < 1536; i += NTH) ((unsigned*)hF)[i] = 0;  // zero both buffers (pads!)

  if (t < NR) {
    int row = perm ? perm[pgrp*NR + t] : (pgrp*NR + t);
    brS[t]  = row;
    idxS[t] = h_lens[row] - 1;   // in [255, 511]
  }
  __syncthreads();

  int maxIdx = idxS[0];
  #pragma unroll
  for (int r = 1; r < NR; ++r) maxIdx = max(maxIdx, idxS[r]);

  const int lane = t & 63;
  const int wv   = t >> 6;                          // 8 waves
  const int col  = lane & 15;
  const int q_a  = lane >> 4;
  const int base = (wv < 2) ? wv*3 : 6 + (wv - 2)*2;  // tiles: w0:0-2 w1:3-5 w2..7: 2 each
  const int nt   = (wv < 2) ? 3 : 2;
  const int g    = col >> 2;                        // col group -> tile base+g
  const int c    = col & 3;                         // batch col (real)
  const bool act = (g < nt);
  const int cidxE = idxS[c];
  const int uA = 4*(base + (act ? g : 0)) + q_a;    // unit owned (if act)
  float cstA = 0.f;

  // ---------------- encoder: 8 -> 256 -> 256 -> 64 ----------------
  if (t < 32) { int r = t >> 3, k = t & 7; xS[k][r] = x[brS[r]*8 + k]; }
  __syncthreads();

  float* z1S = gS;   // [k][4]
  if (t < 256) {
    float acc[NR];
    float b = eb1[t];
    #pragma unroll
    for (int r = 0; r < NR; ++r) acc[r] = b;
    #pragma unroll
    for (int k = 0; k < 8; ++k) { float w = eW1[t*8 + k]; FMA4(acc, w, &xS[k][0]); }
    #pragma unroll
    for (int r = 0; r < NR; ++r) z1S[t*4 + r] = ftanh(acc[r]);
  }
  __syncthreads();
  float* z2S = rnnS; // [k][4]
  if (t < 256) {
    float acc[NR];
    float b = eb2[t];
    #pragma unroll
    for (int r = 0; r < NR; ++r) acc[r] = b;
    const float4* w4 = (const float4*)(eW2 + t*256);
    #pragma unroll 4
    for (int k4 = 0; k4 < 64; ++k4) {
      float4 w = w4[k4];
      FMA4(acc, w.x, z1S + (4*k4+0)*4);
      FMA4(acc, w.y, z1S + (4*k4+1)*4);
      FMA4(acc, w.z, z1S + (4*k4+2)*4);
      FMA4(acc, w.w, z1S + (4*k4+3)*4);
    }
    #pragma unroll
    for (int r = 0; r < NR; ++r) z2S[t*4 + r] = ftanh(acc[r]);
  }
  __syncthreads();
  if (t < 64) {                       // h0 (linear) -> fragment k = 8+t, buffer 0
    float acc[NR];
    float b = eb3[t];
    #pragma unroll
    for (int r = 0; r < NR; ++r) acc[r] = b;
    const float4* w4 = (const float4*)(eW3 + t*256);
    #pragma unroll 4
    for (int k4 = 0; k4 < 64; ++k4) {
      float4 w = w4[k4];
      FMA4(acc, w.x, z2S + (4*k4+0)*4);
      FMA4(acc, w.y, z2S + (4*k4+1)*4);
      FMA4(acc, w.z, z2S + (4*k4+2)*4);
      FMA4(acc, w.w, z2S + (4*k4+3)*4);
    }
    int u = 8 + t;
    #pragma unroll
    for (int r = 0; r < NR; ++r) hF[0][bidx(u, r)] = f2h(acc[r]);
  } else if (t < 96) {                // x part -> k = 0..7, buffer 0
    int tt2 = t - 64; int r = tt2 >> 3, k = tt2 & 7;
    hF[0][bidx(k, r)] = f2h(xS[k][r]);
  }

  // ---------------- weights as fp16 A-fragments (gate-permuted rows) ----------------
  // n' = 4*unit + gate ; src row = gate*72 + unit. A[m=n'][k], k = kt*32+q_a*8+j.
  half8 Af[3][3];
  f32x4 biasq[3];
  #pragma unroll
  for (int i = 0; i < 3; ++i) {
    int ii = (i < nt) ? i : 0;
    int u = 4*(base + ii) + q_a;
    biasq[i].x = b_ih[u]       + b_hh[u];
    biasq[i].y = b_ih[72 + u]  + b_hh[72 + u];
    biasq[i].z = b_ih[144 + u] + b_hh[144 + u];
    biasq[i].w = b_ih[216 + u] + b_hh[216 + u];
    int nprime = (base + ii)*16 + col;
    int srcrow = (nprime & 3)*72 + (nprime >> 2);
    #pragma unroll
    for (int kt = 0; kt < 3; ++kt) {
      union { unsigned short u16[8]; half8 h; } cw;
      #pragma unroll
      for (int j = 0; j < 8; ++j) {
        int k = kt*32 + q_a*8 + j;
        float v = 0.f;
        if (k < 72)      v = W_hh[srcrow*HH + k];
        else if (k < 81) v = W_ih[srcrow*9 + (k - 72)];
        cw.u16[j] = f2h(v);
      }
      Af[i][kt] = cw.h;
    }
  }

  // ---------------- LSTM over time: one barrier per step ----------------
  int step = 0;
  int par = 0;
  __syncthreads();
  for (int chunk = 0; chunk*32 <= maxIdx; ++chunk) {
    // stage 32 steps of rnn_input -> rnnS[tc][r][k]
    for (int e = t; e < 1152; e += NTH) {
      int r = e / 288, pos = e % 288;
      int tc = pos / 9, kk = pos - tc*9;
      rnnS[tc*36 + r*9 + kk] = rnn[brS[r]*4608 + chunk*288 + pos];
    }
    __syncthreads();
    if (t < 36) {                   // xt for first step of chunk -> buffer par
      int r = t / 9, kk = t - r*9;
      hF[par][bidx(72 + kk, r)] = f2h(rnnS[t]);
    }
    __syncthreads();
    int lim = min(31, maxIdx - chunk*32);
    for (int tc = 0; tc <= lim; ++tc, ++step) {
      const int np = par ^ 1;
      half8 bf[3];
      #pragma unroll
      for (int kt = 0; kt < 3; ++kt) {
        int rb = (kt*4 + q_a)*128 + col*8;
        bf[kt] = *(const half8*)&hF[par][rb];
      }
      f32x4 acc[3];
      #pragma unroll
      for (int i = 0; i < 3; ++i) acc[i] = biasq[i];
      #pragma unroll
      for (int kt = 0; kt < 3; ++kt) {
        #pragma unroll
        for (int i = 0; i < 3; ++i) {
          if (i < nt) {
            acc[i] = __builtin_amdgcn_mfma_f32_16x16x32_f16(Af[i][kt], bf[kt], acc[i], 0, 0, 0);
          }
        }
      }
      // fan tile base+1 -> col group 1 (swz4), tile base+2 -> group 2 (swz8)
      float s1x = swz4(acc[1].x), s1y = swz4(acc[1].y), s1z = swz4(acc[1].z), s1w = swz4(acc[1].w);
      float s2x = swz8(acc[2].x), s2y = swz8(acc[2].y), s2z = swz8(acc[2].z), s2w = swz8(acc[2].w);
      if (act) {
        float ig = (g == 0) ? acc[0].x : (g == 1) ? s1x : s2x;
        float fg = (g == 0) ? acc[0].y : (g == 1) ? s1y : s2y;
        float gg = (g == 0) ? acc[0].z : (g == 1) ? s1z : s2z;
        float og = (g == 0) ? acc[0].w : (g == 1) ? s1w : s2w;
        float hv = cellUpd(ig, fg, gg, og, cstA);
        hF[np][bidx(uA, c)] = f2h(hv);
        if (step == cidxE - 1) snapP[c][uA] = hv;
        if (step == cidxE)     snapC[c][uA] = hv;
      }
      if (tc < 31 && t < 36) {      // xt for next step -> buffer np
        int r = t / 9, kk = t - r*9;
        hF[np][bidx(72 + kk, r)] = f2h(rnnS[(tc+1)*36 + t]);
      }
      __syncthreads();
      par = np;
    }
  }

  // ---------------- decoder: 72 -> 288 -> 288 -> 8 ----------------
  if (t < NR) dS[t] = deltas[brS[t]*TT + idxS[t]];
  __syncthreads();

  // build dec_in into hS[u][r]  (288 = 72*4 elements)
  for (int p = t; p < 288; p += NTH) {
    int u = p % 72, r = p / 72;
    float d = dS[r];
    float sp = snapP[r][u], sc = snapC[r][u];
    hS[u][r] = fmaf(d, sc - sp, sp);
  }
  __syncthreads();

  // layer1: 288 x 72
  float* d1S = rnnS; // [n][4]
  for (int n = t; n < 288; n += NTH) {
    float acc[NR];
    float b = db1[n];
    #pragma unroll
    for (int r = 0; r < NR; ++r) acc[r] = b;
    const float4* w4 = (const float4*)(dW1 + n*HH);
    #pragma unroll 2
    for (int k4 = 0; k4 < 18; ++k4) {
      float4 w = w4[k4];
      FMA4(acc, w.x, &hS[4*k4+0][0]);
      FMA4(acc, w.y, &hS[4*k4+1][0]);
      FMA4(acc, w.z, &hS[4*k4+2][0]);
      FMA4(acc, w.w, &hS[4*k4+3][0]);
    }
    #pragma unroll
    for (int r = 0; r < NR; ++r) d1S[n*4 + r] = ftanh(acc[r]);
  }
  __syncthreads();

  // layer2: 288 x 288
  float* d2S = gS;   // [n][4]
  for (int n = t; n < 288; n += NTH) {
    float acc[NR];
    float b = db2[n];
    #pragma unroll
    for (int r = 0; r < NR; ++r) acc[r] = b;
    const float4* w4 = (const float4*)(dW2 + n*288);
    #pragma unroll 4
    for (int k4 = 0; k4 < 72; ++k4) {
      float4 w = w4[k4];
      FMA4(acc, w.x, d1S + (4*k4+0)*4);
      FMA4(acc, w.y, d1S + (4*k4+1)*4);
      FMA4(acc, w.z, d1S + (4*k4+2)*4);
      FMA4(acc, w.w, d1S + (4*k4+3)*4);
    }
    #pragma unroll
    for (int r = 0; r < NR; ++r) d2S[n*4 + r] = ftanh(acc[r]);
  }
  __syncthreads();

  // layer3: 8 x 288 (linear) + scatter store
  if (t < 32) {
    int o = t & 7, r = t >> 3;
    float acc3 = db3[o];
    const float* wr = dW3 + o*288;
    #pragma unroll 4
    for (int k = 0; k < 288; ++k) acc3 = fmaf(wr[k], d2S[k*4 + r], acc3);
    out[brS[r]*8 + o] = acc3;
  }
}

extern "C" void kernel_launch(void* const* d_in, const int* in_sizes, int n_in,
                              void* d_out, int out_size, void* d_ws, size_t ws_size,
                              hipStream_t stream) {
  const float* x      = (const float*)d_in[0];
  const float* rnn    = (const float*)d_in[1];
  const float* deltas = (const float*)d_in[2];
  const int*   h_lens = (const int*)  d_in[3];
  const float* W_ih   = (const float*)d_in[4];
  const float* W_hh   = (const float*)d_in[5];
  const float* b_ih   = (const float*)d_in[6];
  const float* b_hh   = (const float*)d_in[7];
  const float* eW1    = (const float*)d_in[8];
  const float* eb1    = (const float*)d_in[9];
  const float* eW2    = (const float*)d_in[10];
  const float* eb2    = (const float*)d_in[11];
  const float* eW3    = (const float*)d_in[12];
  const float* eb3    = (const float*)d_in[13];
  const float* dW1    = (const float*)d_in[14];
  const float* db1    = (const float*)d_in[15];
  const float* dW2    = (const float*)d_in[16];
  const float* db2    = (const float*)d_in[17];
  const float* dW3    = (const float*)d_in[18];
  const float* db3    = (const float*)d_in[19];
  float* out = (float*)d_out;

  int* perm = nullptr;
  if (ws_size >= 2048 * sizeof(int)) {
    perm = (int*)d_ws;
    cfm_sort<<<1, 256, 0, stream>>>(h_lens, perm);
  }
  cfm_main<<<NBLK, NTH, 0, stream>>>(x, rnn, deltas, h_lens, W_ih, W_hh, b_ih, b_hh,
                                     eW1, eb1, eW2, eb2, eW3, eb3,
                                     dW1, db1, dW2, db2, dW3, db3,
                                     perm, out);
}